// Round 9
// baseline (113.450 us; speedup 1.0000x reference)
//
#include <hip/hip_runtime.h>

// qg_flux, round 9: paired-point (float2) stage loops on interior blocks.
// Even LDS strides (36/38/40/42/44) make horizontal pairs 8B-aligned:
// ds_read_b64 for center row + q, constant-immediate offsets for all
// neighbors, addressing div/mul amortized over 2 points. Edge blocks keep
// the exact scalar path. Structure unchanged: drelaxR -> vleg -> mega.

#define N0 513
#define N1 257
#define NB 16
#define NT 512

#define C0F ((float)(1.0 / 4.006103515625))
#define D0F 4.006103515625f
#define C1F ((float)(1.0 / 4.0244140625))
#define H0SQ 3.814697265625e-06f            // h0^2 = 2^-18, exact
#define INV_DX2 262144.0f                   // 2^18
#define CENTER  1048576.0f                  // 4*2^18
#define INV12S  ((float)(262144.0 / 12.0 * 262144.0))  // INV12 * 2^18

#define LD2(buf, off) (*(const float2*)&(buf)[off])

// Paired 5-pt sweep over W x H (W even): out(r,c) from in at center (r+1,c+1).
// All neighbor offsets are compile-time constants (ds immediate offsets).
template<int W, int H, int SI, int SQ, int SO, bool LAP>
__device__ __forceinline__ void sweep_pair(const float* __restrict__ in,
                                           const float* __restrict__ qq,
                                           float* __restrict__ out, int lid) {
  constexpr int WP = W / 2;
  for (int t = lid; t < WP * H; t += NT) {
    int r = t / WP;
    int c = 2 * (t - r * WP);
    int k = r * SI + c;
    float n0 = in[k + 1],          n1 = in[k + 2];
    float s0 = in[k + 2 * SI + 1], s1 = in[k + 2 * SI + 2];
    float2 m0 = LD2(in, k + SI);
    float2 m1 = LD2(in, k + SI + 2);
    float2 o;
    if constexpr (LAP) {
      o.x = (n0 + s0 + m0.x + m1.x) * INV_DX2 - m0.y * CENTER;
      o.y = (n1 + s1 + m0.y + m1.y) * INV_DX2 - m1.x * CENTER;
    } else {
      int mq = r * SQ + c;
      float q0 = qq[mq], q1 = qq[mq + 1];
      o.x = C0F * (n0 + s0 + m0.x + m1.x - q0);
      o.y = C0F * (n1 + s1 + m0.y + m1.y - q1);
    }
    *(float2*)&out[r * SO + c] = o;
  }
}

// ---------------------------------------------------------------- drelaxR ---
// strides: sIn 40 (38 rows), sQ/sT 38 (36 rows), sP 36 (34 rows, aliases sIn)
template<bool INT>
__device__ __forceinline__ void drelaxR_body(
    const float* __restrict__ P, const float* __restrict__ Q,
    float* __restrict__ outp, float* __restrict__ q1p,
    int ti, int tj, int ic0, int jc0, size_t base, size_t cbase, int lid,
    float* __restrict__ sIn, float* __restrict__ sQ,
    float* __restrict__ sT, float* __restrict__ sP) {
  const int n = N0;
  for (int t = lid; t < 38 * 38; t += NT) {
    int r = t / 38, c = t - r * 38;
    int gi = ti - 3 + r, gj = tj - 3 + c;
    float v;
    if constexpr (INT) v = P[(size_t)gi * n + gj];
    else v = (gi >= 0 && gi < n && gj >= 0 && gj < n) ? P[(size_t)gi * n + gj] : 0.f;
    sIn[r * 40 + c] = v;
  }
  for (int t = lid; t < 36 * 36; t += NT) {
    int r = t / 36, c = t - r * 36;
    int gi = ti - 2 + r, gj = tj - 2 + c;
    float v;
    if constexpr (INT) v = Q[(size_t)gi * n + gj] * H0SQ;
    else v = (gi >= 0 && gi < n && gj >= 0 && gj < n) ? Q[(size_t)gi * n + gj] * H0SQ : 0.f;
    sQ[r * 38 + c] = v;
  }
  __syncthreads();
  if constexpr (INT) {
    sweep_pair<36, 36, 40, 38, 38, false>(sIn, sQ, sT, lid);
  } else {
    for (int t = lid; t < 36 * 36; t += NT) {
      int r = t / 36, c = t - r * 36;
      float v = 0.f;
      if ((ti - 2 + r) >= 1 && (ti - 2 + r) < n - 1 && (tj - 2 + c) >= 1 && (tj - 2 + c) < n - 1)
        v = C0F * (sIn[r * 40 + c + 1] + sIn[(r + 2) * 40 + c + 1] +
                   sIn[(r + 1) * 40 + c] + sIn[(r + 1) * 40 + c + 2] - sQ[r * 38 + c]);
      sT[r * 38 + c] = v;
    }
  }
  __syncthreads();
  if constexpr (INT) {
    // s2 paired + fused store (in sT(38), q sQ(38)+39, out sP(36))
    for (int t = lid; t < 17 * 34; t += NT) {
      int r = t / 17;
      int c = 2 * (t - r * 17);
      int k = r * 38 + c;
      float n0 = sT[k + 1],  n1 = sT[k + 2];
      float s0 = sT[k + 77], s1 = sT[k + 78];
      float2 m0 = LD2(sT, k + 38);
      float2 m1 = LD2(sT, k + 40);
      float q0 = sQ[k + 39], q1 = sQ[k + 40];
      float v0 = C0F * (n0 + s0 + m0.x + m1.x - q0);
      float v1 = C0F * (n1 + s1 + m0.y + m1.y - q1);
      float2 o; o.x = v0; o.y = v1;
      *(float2*)&sP[r * 36 + c] = o;
      if (r >= 1 && r <= 32) {
        size_t gb = base + (size_t)(ti - 1 + r) * n + (tj - 1);
        if (c >= 1 && c <= 32) outp[gb + c] = v0;
        if (c <= 31)           outp[gb + c + 1] = v1;
      }
    }
  } else {
    for (int t = lid; t < 34 * 34; t += NT) {
      int r = t / 34, c = t - r * 34;
      float v = 0.f;
      if ((ti - 1 + r) >= 1 && (ti - 1 + r) < n - 1 && (tj - 1 + c) >= 1 && (tj - 1 + c) < n - 1)
        v = C0F * (sT[r * 38 + c + 1] + sT[(r + 2) * 38 + c + 1] +
                   sT[(r + 1) * 38 + c] + sT[(r + 1) * 38 + c + 2] - sQ[(r + 1) * 38 + c + 1]);
      sP[r * 36 + c] = v;
      if (r >= 1 && r <= 32 && c >= 1 && c <= 32 && (ti - 1 + r) < n && (tj - 1 + c) < n)
        outp[base + (size_t)(ti - 1 + r) * n + (tj - 1 + c)] = v;
    }
  }
  __syncthreads();
  if (lid < 256) {
    int cy = lid >> 4, cx = lid & 15;
    int ic = ic0 + cy, jc = jc0 + cx;
    if (INT || (ic < N1 && jc < N1)) {
      float v = 0.f;
      if (INT || (ic >= 1 && ic < N1 - 1 && jc >= 1 && jc < N1 - 1)) {
        int r = 2 * cy + 1, c = 2 * cx + 1;
        v = 4.f * (D0F * sP[r * 36 + c] - sP[(r - 1) * 36 + c] - sP[(r + 1) * 36 + c]
                   - sP[r * 36 + c - 1] - sP[r * 36 + c + 1] + sQ[(r + 1) * 38 + c + 1]);
      }
      q1p[cbase + (size_t)ic * N1 + jc] = v;
    }
  }
}

__global__ __launch_bounds__(NT) void drelaxR_k(
    const float* __restrict__ psi, const float* __restrict__ Qg,
    float* __restrict__ out, float* __restrict__ q1) {
  __shared__ float smem[38 * 40 + 36 * 38 + 36 * 38];
  float* sIn = smem;
  float* sQ  = smem + 38 * 40;
  float* sT  = sQ + 36 * 38;
  float* sP  = smem;               // alias sIn (dead after s1)
  int bx = blockIdx.x, by = blockIdx.y;
  int ti = by * 32, tj = bx * 32;
  size_t base = (size_t)blockIdx.z * (N0 * N0);
  size_t cbase = (size_t)blockIdx.z * (N1 * N1);
  int lid = threadIdx.y * 32 + threadIdx.x;
  bool inter = (bx >= 1 && bx <= 14 && by >= 1 && by <= 14);
  if (inter)
    drelaxR_body<true>(psi + base, Qg + base, out, q1, ti, tj, 16 * by, 16 * bx,
                       base, cbase, lid, sIn, sQ, sT, sP);
  else
    drelaxR_body<false>(psi + base, Qg + base, out, q1, ti, tj, 16 * by, 16 * bx,
                        base, cbase, lid, sIn, sQ, sT, sP);
}

// ------------------------------------------------------- shared coarse prep --
// bufB stride 42 (40 rows), bufA stride 44 (42 rows), sq1 26, sp1 24.
template<bool INT>
__device__ __forceinline__ void coarse_and_v(
    const float* __restrict__ P, const float* __restrict__ Q,
    const float* __restrict__ q1,
    int ti, int tj, int c0i, int c0j, int lid,
    float* __restrict__ bufA, float* __restrict__ bufB,
    float* __restrict__ sq1, float* __restrict__ sp1) {
  const int n = N0;
  for (int t = lid; t < 25 * 25; t += NT) {
    int r = t / 25, c = t - r * 25;
    int ci = c0i - 1 + r, cj = c0j - 1 + c;
    float v;
    if constexpr (INT) v = q1[(size_t)ci * N1 + cj];
    else v = (ci >= 0 && ci < N1 && cj >= 0 && cj < N1) ? q1[(size_t)ci * N1 + cj] : 0.f;
    sq1[r * 26 + c] = v;
  }
  for (int t = lid; t < 40 * 40; t += NT) {
    int r = t / 40, c = t - r * 40;
    int gi = ti - 4 + r, gj = tj - 4 + c;
    float v;
    if constexpr (INT) v = Q[(size_t)gi * n + gj] * H0SQ;
    else v = (gi >= 0 && gi < n && gj >= 0 && gj < n) ? Q[(size_t)gi * n + gj] * H0SQ : 0.f;
    bufB[r * 42 + c] = v;
  }
  __syncthreads();
  for (int t = lid; t < 23 * 23; t += NT) {
    int r = t / 23, c = t - r * 23;
    float v = 0.f;
    if (INT || ((c0i + r) >= 1 && (c0i + r) < N1 - 1 && (c0j + c) >= 1 && (c0j + c) < N1 - 1))
      v = C1F * (-C1F * (sq1[r * 26 + c + 1] + sq1[(r + 2) * 26 + c + 1] +
                         sq1[(r + 1) * 26 + c] + sq1[(r + 1) * 26 + c + 2])
                 - sq1[(r + 1) * 26 + c + 1]);
    sp1[r * 24 + c] = v;
  }
  __syncthreads();
  for (int t = lid; t < 42 * 42; t += NT) {
    int r = t / 42, c = t - r * 42;
    int gi = ti - 5 + r, gj = tj - 5 + c;
    float v = 0.f;
    if (INT || (gi >= 0 && gi < n && gj >= 0 && gj < n)) {
      int r1 = (gi >> 1) - c0i, c1 = (gj >> 1) - c0j;
      float a = sp1[r1 * 24 + c1],       b = sp1[r1 * 24 + c1 + 1];
      float e = sp1[(r1 + 1) * 24 + c1], d = sp1[(r1 + 1) * 24 + c1 + 1];
      float wx = (gj & 1) ? 0.5f : 0.f, wy = (gi & 1) ? 0.5f : 0.f;
      float r0 = a + wx * (b - a), rr = e + wx * (d - e);
      v = P[(size_t)gi * n + gj] + (r0 + wy * (rr - r0));
    }
    bufA[r * 44 + c] = v;
  }
  __syncthreads();
}

// ------------------------------------------------------------------- vleg ---
template<bool INT>
__device__ __forceinline__ void vleg_body(
    const float* __restrict__ P, const float* __restrict__ Q,
    const float* __restrict__ q1, float* __restrict__ outp, float* __restrict__ q1o,
    int ti, int tj, int c0i, int c0j, int ic0, int jc0,
    size_t base, size_t cbase, int lid,
    float* __restrict__ bufA, float* __restrict__ bufB,
    float* __restrict__ bufC, float* __restrict__ bufD) {
  const int n = N0;
  coarse_and_v<INT>(P, Q, q1, ti, tj, c0i, c0j, lid, bufA, bufB, bufD, bufD + 25 * 26);
  if constexpr (INT) {
    sweep_pair<40, 40, 44, 42, 42, false>(bufA, bufB, bufC, lid);        // s1
    __syncthreads();
    sweep_pair<38, 38, 42, 42, 40, false>(bufC, bufB + 43, bufD, lid);   // s2
    __syncthreads();
    sweep_pair<36, 36, 40, 42, 38, false>(bufD, bufB + 86, bufA, lid);   // s3
    __syncthreads();
    // s4 paired + fused store: in bufA(38), q bufB(42)+129, out bufC(36)
    for (int t = lid; t < 17 * 34; t += NT) {
      int r = t / 17;
      int c = 2 * (t - r * 17);
      int k = r * 38 + c;
      float n0 = bufA[k + 1],  n1 = bufA[k + 2];
      float s0 = bufA[k + 77], s1 = bufA[k + 78];
      float2 m0 = LD2(bufA, k + 38);
      float2 m1 = LD2(bufA, k + 40);
      int mq = r * 42 + c + 129;
      float q0 = bufB[mq], q1v = bufB[mq + 1];
      float v0 = C0F * (n0 + s0 + m0.x + m1.x - q0);
      float v1 = C0F * (n1 + s1 + m0.y + m1.y - q1v);
      float2 o; o.x = v0; o.y = v1;
      *(float2*)&bufC[r * 36 + c] = o;
      if (r >= 1 && r <= 32) {
        size_t gb = base + (size_t)(ti - 1 + r) * n + (tj - 1);
        if (c >= 1 && c <= 32) outp[gb + c] = v0;
        if (c <= 31)           outp[gb + c + 1] = v1;
      }
    }
    __syncthreads();
  } else {
    for (int t = lid; t < 40 * 40; t += NT) {   // s1
      int r = t / 40, c = t - r * 40;
      float v = 0.f;
      if ((ti - 4 + r) >= 1 && (ti - 4 + r) < n - 1 && (tj - 4 + c) >= 1 && (tj - 4 + c) < n - 1)
        v = C0F * (bufA[r * 44 + c + 1] + bufA[(r + 2) * 44 + c + 1] +
                   bufA[(r + 1) * 44 + c] + bufA[(r + 1) * 44 + c + 2] - bufB[r * 42 + c]);
      bufC[r * 42 + c] = v;
    }
    __syncthreads();
    for (int t = lid; t < 38 * 38; t += NT) {   // s2
      int r = t / 38, c = t - r * 38;
      float v = 0.f;
      if ((ti - 3 + r) >= 1 && (ti - 3 + r) < n - 1 && (tj - 3 + c) >= 1 && (tj - 3 + c) < n - 1)
        v = C0F * (bufC[r * 42 + c + 1] + bufC[(r + 2) * 42 + c + 1] +
                   bufC[(r + 1) * 42 + c] + bufC[(r + 1) * 42 + c + 2] - bufB[(r + 1) * 42 + c + 1]);
      bufD[r * 40 + c] = v;
    }
    __syncthreads();
    for (int t = lid; t < 36 * 36; t += NT) {   // s3
      int r = t / 36, c = t - r * 36;
      float v = 0.f;
      if ((ti - 2 + r) >= 1 && (ti - 2 + r) < n - 1 && (tj - 2 + c) >= 1 && (tj - 2 + c) < n - 1)
        v = C0F * (bufD[r * 40 + c + 1] + bufD[(r + 2) * 40 + c + 1] +
                   bufD[(r + 1) * 40 + c] + bufD[(r + 1) * 40 + c + 2] - bufB[(r + 2) * 42 + c + 2]);
      bufA[r * 38 + c] = v;
    }
    __syncthreads();
    for (int t = lid; t < 34 * 34; t += NT) {   // s4 + store
      int r = t / 34, c = t - r * 34;
      float v = 0.f;
      if ((ti - 1 + r) >= 1 && (ti - 1 + r) < n - 1 && (tj - 1 + c) >= 1 && (tj - 1 + c) < n - 1)
        v = C0F * (bufA[r * 38 + c + 1] + bufA[(r + 2) * 38 + c + 1] +
                   bufA[(r + 1) * 38 + c] + bufA[(r + 1) * 38 + c + 2] - bufB[(r + 3) * 42 + c + 3]);
      bufC[r * 36 + c] = v;
      if (r >= 1 && r <= 32 && c >= 1 && c <= 32 && (ti - 1 + r) < n && (tj - 1 + c) < n)
        outp[base + (size_t)(ti - 1 + r) * n + (tj - 1 + c)] = v;
    }
    __syncthreads();
  }
  if (lid < 256) {
    int cy = lid >> 4, cx = lid & 15;
    int ic = ic0 + cy, jc = jc0 + cx;
    if (INT || (ic < N1 && jc < N1)) {
      float v = 0.f;
      if (INT || (ic >= 1 && ic < N1 - 1 && jc >= 1 && jc < N1 - 1)) {
        int r = 2 * cy + 1, c = 2 * cx + 1;
        v = 4.f * (D0F * bufC[r * 36 + c] - bufC[(r - 1) * 36 + c] - bufC[(r + 1) * 36 + c]
                   - bufC[r * 36 + c - 1] - bufC[r * 36 + c + 1]
                   + bufB[(2 * cy + 4) * 42 + 2 * cx + 4]);
      }
      q1o[cbase + (size_t)ic * N1 + jc] = v;
    }
  }
}

__global__ __launch_bounds__(NT) void vleg_k(
    const float* __restrict__ psi, const float* __restrict__ Qg,
    const float* __restrict__ q1g, float* __restrict__ out, float* __restrict__ q1o) {
  __shared__ float bufA[42 * 44];
  __shared__ float bufB[40 * 42];
  __shared__ float bufC[40 * 42];
  __shared__ float bufD[38 * 40];
  int bx = blockIdx.x, by = blockIdx.y;
  int ti = by * 32, tj = bx * 32;
  int c0i = 16 * by - 3, c0j = 16 * bx - 3;
  size_t base = (size_t)blockIdx.z * (N0 * N0);
  size_t cbase = (size_t)blockIdx.z * (N1 * N1);
  const float* q1 = q1g + cbase;
  int lid = threadIdx.y * 32 + threadIdx.x;
  bool inter = (bx >= 1 && bx <= 14 && by >= 1 && by <= 14);
  if (inter)
    vleg_body<true>(psi + base, Qg + base, q1, out, q1o, ti, tj, c0i, c0j,
                    16 * by, 16 * bx, base, cbase, lid, bufA, bufB, bufC, bufD);
  else
    vleg_body<false>(psi + base, Qg + base, q1, out, q1o, ti, tj, c0i, c0j,
                     16 * by, 16 * bx, base, cbase, lid, bufA, bufB, bufC, bufD);
}

// ------------------------------------------------------------------- mega ---
template<bool INT>
__device__ __forceinline__ void mega_body(
    const float* __restrict__ P, const float* __restrict__ Q,
    const float* __restrict__ q1, const float* __restrict__ CT,
    float* __restrict__ psi_out, float* __restrict__ qf_out,
    int ti, int tj, int c0i, int c0j, size_t base, int lid,
    float* __restrict__ bufA, float* __restrict__ bufB,
    float* __restrict__ bufC, float* __restrict__ bufD) {
  const int n = N0;
  coarse_and_v<INT>(P, Q, q1, ti, tj, c0i, c0j, lid, bufA, bufB, bufD, bufD + 25 * 26);
  if constexpr (INT) {
    sweep_pair<40, 40, 44, 42, 42, false>(bufA, bufB, bufC, lid);        // s1
    __syncthreads();
    sweep_pair<38, 38, 42, 42, 40, false>(bufC, bufB + 43, bufD, lid);   // s2
    __syncthreads();
    sweep_pair<36, 36, 40, 42, 38, true>(bufD, bufB, bufA, lid);         // Z
    __syncthreads();
    sweep_pair<34, 34, 38, 42, 36, true>(bufA, bufB, bufC, lid);         // Z2
    __syncthreads();
    // paired epilogue: 16 pair-cols x 32 rows = 512 threads, one slot each
    {
      int txp = lid & 15, yy = lid >> 4;
      int cc = 2 * txp;
      int i = ti + yy, j0 = tj + cc;
      size_t idx = base + (size_t)i * n + j0;
      int kd = (yy + 2) * 40 + cc + 2;
      float2 d00 = LD2(bufD, kd),      d01 = LD2(bufD, kd + 2);
      float2 d10 = LD2(bufD, kd + 40), d11 = LD2(bufD, kd + 42);
      float2 d20 = LD2(bufD, kd + 80), d21 = LD2(bufD, kd + 82);
      psi_out[idx]     = d10.y;
      psi_out[idx + 1] = d11.x;
      float2 z1 = LD2(bufA, (yy + 2) * 38 + cc + 2);
      int kc = (yy + 1) * 36 + cc;
      float2 zc0 = LD2(bufC, kc), zc1 = LD2(bufC, kc + 2);
      float zN0 = bufC[kc - 36 + 1], zN1 = bufC[kc - 36 + 2];
      float zS0 = bufC[kc + 36 + 1], zS1 = bufC[kc + 36 + 2];
      float z4_0 = (zc0.x + zc1.x + zN0 + zS0) * INV_DX2 - zc0.y * CENTER;
      float z4_1 = (zc0.y + zc1.y + zN1 + zS1) * INV_DX2 - zc1.x * CENTER;
      int kb = (yy + 3) * 42 + cc + 3;
      float  bm0 = bufB[kb];       float2 bm12 = LD2(bufB, kb + 1);  float bm3 = bufB[kb + 3];
      float  b00 = bufB[kb + 42];  float2 b012 = LD2(bufB, kb + 43); float b03 = bufB[kb + 45];
      float  bp0 = bufB[kb + 84];  float2 bp12 = LD2(bufB, kb + 85); float bp3 = bufB[kb + 87];
      // point 0
      float J0 = (d10.x - d00.y) * bm0
               + (d00.x + d10.x - d01.x - d11.x) * bm12.x
               + (d00.y - d11.x) * bm12.y
               + (d20.x + d20.y - d00.x - d00.y) * b00
               + (d00.y + d01.x - d20.y - d21.x) * b012.y
               + (d20.y - d10.x) * bp0
               + (d11.x + d21.x - d10.x - d20.x) * bp12.x
               + (d11.x - d20.y) * bp12.y;
      J0 *= INV12S;
      float ct0 = CT[(size_t)i * n + j0];
      qf_out[idx] = -J0 - 1e-6f * z1.x + 1e-8f * zc0.y - 2e-11f * z4_0 + ct0
                    - 256.0f * (d11.x - d10.x);
      // point 1
      float J1 = (d10.y - d01.x) * bm12.x
               + (d00.y + d10.y - d01.y - d11.y) * bm12.y
               + (d01.x - d11.y) * bm3
               + (d20.y + d21.x - d00.y - d01.x) * b012.x
               + (d01.x + d01.y - d21.x - d21.y) * b03
               + (d21.x - d10.y) * bp12.x
               + (d11.y + d21.y - d10.y - d20.y) * bp12.y
               + (d11.y - d21.x) * bp3;
      J1 *= INV12S;
      float ct1 = CT[(size_t)i * n + j0 + 1];
      qf_out[idx + 1] = -J1 - 1e-6f * z1.y + 1e-8f * zc1.x - 2e-11f * z4_1 + ct1
                        - 256.0f * (d11.y - d10.y);
    }
  } else {
    for (int t = lid; t < 40 * 40; t += NT) {   // s1
      int r = t / 40, c = t - r * 40;
      float v = 0.f;
      if ((ti - 4 + r) >= 1 && (ti - 4 + r) < n - 1 && (tj - 4 + c) >= 1 && (tj - 4 + c) < n - 1)
        v = C0F * (bufA[r * 44 + c + 1] + bufA[(r + 2) * 44 + c + 1] +
                   bufA[(r + 1) * 44 + c] + bufA[(r + 1) * 44 + c + 2] - bufB[r * 42 + c]);
      bufC[r * 42 + c] = v;
    }
    __syncthreads();
    for (int t = lid; t < 38 * 38; t += NT) {   // s2
      int r = t / 38, c = t - r * 38;
      float v = 0.f;
      if ((ti - 3 + r) >= 1 && (ti - 3 + r) < n - 1 && (tj - 3 + c) >= 1 && (tj - 3 + c) < n - 1)
        v = C0F * (bufC[r * 42 + c + 1] + bufC[(r + 2) * 42 + c + 1] +
                   bufC[(r + 1) * 42 + c] + bufC[(r + 1) * 42 + c + 2] - bufB[(r + 1) * 42 + c + 1]);
      bufD[r * 40 + c] = v;
    }
    __syncthreads();
    for (int t = lid; t < 36 * 36; t += NT) {   // Z
      int r = t / 36, c = t - r * 36;
      float v = 0.f;
      if ((ti - 2 + r) >= 1 && (ti - 2 + r) < n - 1 && (tj - 2 + c) >= 1 && (tj - 2 + c) < n - 1)
        v = (bufD[r * 40 + c + 1] + bufD[(r + 2) * 40 + c + 1] +
             bufD[(r + 1) * 40 + c] + bufD[(r + 1) * 40 + c + 2]) * INV_DX2
            - bufD[(r + 1) * 40 + c + 1] * CENTER;
      bufA[r * 38 + c] = v;
    }
    __syncthreads();
    for (int t = lid; t < 34 * 34; t += NT) {   // Z2
      int r = t / 34, c = t - r * 34;
      float v = 0.f;
      if ((ti - 1 + r) >= 1 && (ti - 1 + r) < n - 1 && (tj - 1 + c) >= 1 && (tj - 1 + c) < n - 1)
        v = (bufA[r * 38 + c + 1] + bufA[(r + 2) * 38 + c + 1] +
             bufA[(r + 1) * 38 + c] + bufA[(r + 1) * 38 + c + 2]) * INV_DX2
            - bufA[(r + 1) * 38 + c + 1] * CENTER;
      bufC[r * 36 + c] = v;
    }
    __syncthreads();
    int tx = lid & 31, ty = lid >> 5;
    #pragma unroll
    for (int s = 0; s < 2; s++) {
      int yy = ty + 16 * s;
      int i = ti + yy, j = tj + tx;
      if (i >= n || j >= n) continue;
      size_t idx = base + (size_t)i * n + j;
      int pr = yy + 3, pc = tx + 3;
      psi_out[idx] = bufD[pr * 40 + pc];
      float qv = 0.f;
      if (i >= 1 && i < n - 1 && j >= 1 && j < n - 1) {
        float z1v = bufA[(yy + 2) * 38 + tx + 2];
        int r2 = yy + 1, c2 = tx + 1;
        float z2v = bufC[r2 * 36 + c2];
        float z4 = (bufC[r2 * 36 + c2 - 1] + bufC[r2 * 36 + c2 + 1] +
                    bufC[(r2 - 1) * 36 + c2] + bufC[(r2 + 1) * 36 + c2]) * INV_DX2
                   - z2v * CENTER;
        float Amm = bufD[(pr - 1) * 40 + pc - 1], Am0 = bufD[(pr - 1) * 40 + pc],
              Amp = bufD[(pr - 1) * 40 + pc + 1];
        float A0m = bufD[pr * 40 + pc - 1], A0p = bufD[pr * 40 + pc + 1];
        float Apm = bufD[(pr + 1) * 40 + pc - 1], Ap0 = bufD[(pr + 1) * 40 + pc],
              App = bufD[(pr + 1) * 40 + pc + 1];
        int qr = yy + 4, qc = tx + 4;
        float J = (A0m - Am0) * bufB[(qr - 1) * 42 + qc - 1]
                + (Amm + A0m - Amp - A0p) * bufB[(qr - 1) * 42 + qc]
                + (Am0 - A0p) * bufB[(qr - 1) * 42 + qc + 1]
                + (Apm + Ap0 - Amm - Am0) * bufB[qr * 42 + qc - 1]
                + (Am0 + Amp - Ap0 - App) * bufB[qr * 42 + qc + 1]
                + (Ap0 - A0m) * bufB[(qr + 1) * 42 + qc - 1]
                + (A0p + App - A0m - Apm) * bufB[(qr + 1) * 42 + qc]
                + (A0p - Ap0) * bufB[(qr + 1) * 42 + qc + 1];
        J *= INV12S;
        float ct = CT[(size_t)i * n + j];
        qv = -J - 1e-6f * z1v + 1e-8f * z2v - 2e-11f * z4 + ct - 256.0f * (A0p - A0m);
      }
      qf_out[idx] = qv;
    }
  }
}

__global__ __launch_bounds__(NT) void mega_k(
    const float* __restrict__ psi, const float* __restrict__ Qg,
    const float* __restrict__ q1g, const float* __restrict__ CT,
    float* __restrict__ psi_out, float* __restrict__ qf_out) {
  __shared__ float bufA[42 * 44];
  __shared__ float bufB[40 * 42];
  __shared__ float bufC[40 * 42];
  __shared__ float bufD[38 * 40];
  int bx = blockIdx.x, by = blockIdx.y;
  int ti = by * 32, tj = bx * 32;
  int c0i = 16 * by - 3, c0j = 16 * bx - 3;
  size_t base = (size_t)blockIdx.z * (N0 * N0);
  const float* q1 = q1g + (size_t)blockIdx.z * (N1 * N1);
  int lid = threadIdx.y * 32 + threadIdx.x;
  bool inter = (bx >= 1 && bx <= 14 && by >= 1 && by <= 14);
  if (inter)
    mega_body<true>(psi + base, Qg + base, q1, CT, psi_out, qf_out,
                    ti, tj, c0i, c0j, base, lid, bufA, bufB, bufC, bufD);
  else
    mega_body<false>(psi + base, Qg + base, q1, CT, psi_out, qf_out,
                     ti, tj, c0i, c0j, base, lid, bufA, bufB, bufC, bufD);
}

extern "C" void kernel_launch(void* const* d_in, const int* in_sizes, int n_in,
                              void* d_out, int out_size, void* d_ws, size_t ws_size,
                              hipStream_t stream) {
  const float* PSIG = (const float*)d_in[1];
  const float* Q    = (const float*)d_in[2];
  const float* CT   = (const float*)d_in[3];

  float* ws = (float*)d_ws;
  size_t f0 = (size_t)NB * N0 * N0;
  size_t f1 = (size_t)NB * N1 * N1;
  float* pA  = ws;
  float* pB  = pA + f0;
  float* q1a = pB + f0;
  float* q1b = q1a + f1;

  dim3 blk(32, 16, 1), grd(17, 17, NB);

  drelaxR_k<<<grd, blk, 0, stream>>>(PSIG, Q, pA, q1a);      // cycle-1 down
  vleg_k<<<grd, blk, 0, stream>>>(pA, Q, q1a, pB, q1b);      // c1 up + c2 down
  float* psi_out = (float*)d_out;
  float* qf_out  = psi_out + f0;
  mega_k<<<grd, blk, 0, stream>>>(pB, Q, q1b, CT, psi_out, qf_out);  // c2 up + flux
}

// Round 10
// 100.562 us; speedup vs baseline: 1.1282x; 1.1282x over previous
//
#include <hip/hip_runtime.h>

// qg_flux, round 10: round-8 structure + vertical 4-row-strip stage loops on
// interior blocks (single-pass per stage, register-chained N/S, immediate
// LDS offsets). Edge blocks keep the exact round-8 scalar path.

#define N0 513
#define N1 257
#define NB 16
#define NT 512

#define C0F ((float)(1.0 / 4.006103515625))
#define D0F 4.006103515625f
#define C1F ((float)(1.0 / 4.0244140625))
#define H0SQ 3.814697265625e-06f            // h0^2 = 2^-18, exact
#define INV_DX2 262144.0f                   // 2^18
#define CENTER  1048576.0f                  // 4*2^18
#define INV12S  ((float)(262144.0 / 12.0 * 262144.0))  // INV12 * 2^18

// ---- vertical-strip helpers (interior blocks only; no bounds checks) -------

// stage W x H region from global g (stride GS) at origin (oi,oj) into LDS s.
template<int W, int H, int SL, int GS, bool SC>
__device__ __forceinline__ void stage_v(const float* __restrict__ g,
                                        int oi, int oj,
                                        float* __restrict__ s, int lid) {
  constexpr int RB = (H + 3) / 4;
  if (lid < W * RB) {
    int c = lid % W, rb = lid / W, r0 = rb * 4;
    const float* gp = g + (size_t)(oi + r0) * GS + (oj + c);
    #pragma unroll
    for (int k = 0; k < 4; k++) {
      if constexpr (H % 4 != 0) { if (r0 + k >= H) break; }
      float v = gp[k * GS];
      s[(r0 + k) * SL + c] = SC ? v * H0SQ : v;
    }
  }
}

// 5-pt sweep over W x H: out(r,c) from in centered at (r+1,c+1).
template<int W, int H, int SI, int SQ, int SO, bool LAP>
__device__ __forceinline__ void sweep_v(const float* __restrict__ in,
                                        const float* __restrict__ qq,
                                        float* __restrict__ out, int lid) {
  constexpr int RB = (H + 3) / 4;
  if (lid < W * RB) {
    int c = lid % W, rb = lid / W, r0 = rb * 4;
    const float* colp = in + r0 * SI + (c + 1);
    float vn = colp[0];
    float vc = colp[SI];
    #pragma unroll
    for (int k = 0; k < 4; k++) {
      if constexpr (H % 4 != 0) { if (r0 + k >= H) break; }
      int r = r0 + k;
      float vs = colp[(k + 2) * SI];
      float wv = in[(r + 1) * SI + c];
      float ev = in[(r + 1) * SI + c + 2];
      float o;
      if constexpr (LAP)
        o = (vn + vs + wv + ev) * INV_DX2 - vc * CENTER;
      else
        o = C0F * (vn + vs + wv + ev - qq[r * SQ + c]);
      out[r * SO + c] = o;
      vn = vc; vc = vs;
    }
  }
}

// final relax sweep (34x34) + fused global store of rows/cols 1..32.
template<int SI, int SQ, int SO>
__device__ __forceinline__ void sweep_v_store(const float* __restrict__ in,
                                              const float* __restrict__ qq,
                                              float* __restrict__ out,
                                              float* __restrict__ gout,
                                              int ti, int tj, int lid) {
  constexpr int W = 34, H = 34, RB = 9;
  if (lid < W * RB) {
    int c = lid % W, rb = lid / W, r0 = rb * 4;
    const float* colp = in + r0 * SI + (c + 1);
    float vn = colp[0];
    float vc = colp[SI];
    bool cin = (c >= 1 && c <= 32);
    #pragma unroll
    for (int k = 0; k < 4; k++) {
      if (r0 + k >= H) break;
      int r = r0 + k;
      float vs = colp[(k + 2) * SI];
      float wv = in[(r + 1) * SI + c];
      float ev = in[(r + 1) * SI + c + 2];
      float o = C0F * (vn + vs + wv + ev - qq[r * SQ + c]);
      out[r * SO + c] = o;
      if (cin && r >= 1 && r <= 32)
        gout[(size_t)(ti - 1 + r) * N0 + (tj - 1 + c)] = o;
      vn = vc; vc = vs;
    }
  }
}

// prolong: bufA(42x42, stride 43, org ti-5) = P + up(sp1)
__device__ __forceinline__ void prolong_v(const float* __restrict__ P,
                                          const float* __restrict__ sp1,
                                          float* __restrict__ bufA,
                                          int ti, int tj, int c0i, int c0j,
                                          int lid) {
  constexpr int W = 42, H = 42, RB = 11;
  if (lid < W * RB) {
    int c = lid % W, rb = lid / W, r0 = rb * 4;
    int gj = tj - 5 + c;
    int c1 = (gj >> 1) - c0j;
    float wx = (gj & 1) ? 0.5f : 0.f;
    const float* gp = P + (size_t)(ti - 5 + r0) * N0 + gj;
    #pragma unroll
    for (int k = 0; k < 4; k++) {
      if (r0 + k >= H) break;
      int r = r0 + k;
      int gi = ti - 5 + r;
      int r1 = (gi >> 1) - c0i;
      float a = sp1[r1 * 24 + c1],       b = sp1[r1 * 24 + c1 + 1];
      float e = sp1[(r1 + 1) * 24 + c1], d = sp1[(r1 + 1) * 24 + c1 + 1];
      float wy = (gi & 1) ? 0.5f : 0.f;
      float t0 = a + wx * (b - a), t1 = e + wx * (d - e);
      bufA[r * 43 + c] = gp[k * N0] + (t0 + wy * (t1 - t0));
    }
  }
}

// ---------------------------------------------------------------- drelaxR ---
template<bool INT>
__device__ __forceinline__ void drelaxR_body(
    const float* __restrict__ P, const float* __restrict__ Q,
    float* __restrict__ outp, float* __restrict__ q1p,
    int ti, int tj, int ic0, int jc0, size_t base, size_t cbase, int lid,
    float* __restrict__ sIn, float* __restrict__ sQ,
    float* __restrict__ sT, float* __restrict__ sP) {
  const int n = N0;
  if constexpr (INT) {
    stage_v<38, 38, 39, N0, false>(P, ti - 3, tj - 3, sIn, lid);
    stage_v<36, 36, 37, N0, true>(Q, ti - 2, tj - 2, sQ, lid);
    __syncthreads();
    sweep_v<36, 36, 39, 37, 37, false>(sIn, sQ, sT, lid);
    __syncthreads();
    sweep_v_store<37, 37, 35>(sT, sQ + 38, sP, outp + base, ti, tj, lid);
    __syncthreads();
  } else {
    for (int t = lid; t < 38 * 38; t += NT) {
      int r = t / 38, c = t - r * 38;
      int gi = ti - 3 + r, gj = tj - 3 + c;
      sIn[r * 39 + c] = (gi >= 0 && gi < n && gj >= 0 && gj < n) ? P[(size_t)gi * n + gj] : 0.f;
    }
    for (int t = lid; t < 36 * 36; t += NT) {
      int r = t / 36, c = t - r * 36;
      int gi = ti - 2 + r, gj = tj - 2 + c;
      sQ[r * 37 + c] = (gi >= 0 && gi < n && gj >= 0 && gj < n) ? Q[(size_t)gi * n + gj] * H0SQ : 0.f;
    }
    __syncthreads();
    for (int t = lid; t < 36 * 36; t += NT) {
      int r = t / 36, c = t - r * 36;
      float v = 0.f;
      if ((ti - 2 + r) >= 1 && (ti - 2 + r) < n - 1 && (tj - 2 + c) >= 1 && (tj - 2 + c) < n - 1)
        v = C0F * (sIn[r * 39 + c + 1] + sIn[(r + 2) * 39 + c + 1] +
                   sIn[(r + 1) * 39 + c] + sIn[(r + 1) * 39 + c + 2] - sQ[r * 37 + c]);
      sT[r * 37 + c] = v;
    }
    __syncthreads();
    for (int t = lid; t < 34 * 34; t += NT) {
      int r = t / 34, c = t - r * 34;
      float v = 0.f;
      if ((ti - 1 + r) >= 1 && (ti - 1 + r) < n - 1 && (tj - 1 + c) >= 1 && (tj - 1 + c) < n - 1)
        v = C0F * (sT[r * 37 + c + 1] + sT[(r + 2) * 37 + c + 1] +
                   sT[(r + 1) * 37 + c] + sT[(r + 1) * 37 + c + 2] - sQ[(r + 1) * 37 + c + 1]);
      sP[r * 35 + c] = v;
      if (r >= 1 && r <= 32 && c >= 1 && c <= 32 && (ti - 1 + r) < n && (tj - 1 + c) < n)
        outp[base + (size_t)(ti - 1 + r) * n + (tj - 1 + c)] = v;
    }
    __syncthreads();
  }
  if (lid < 256) {
    int cy = lid >> 4, cx = lid & 15;
    int ic = ic0 + cy, jc = jc0 + cx;
    if (INT || (ic < N1 && jc < N1)) {
      float v = 0.f;
      if (INT || (ic >= 1 && ic < N1 - 1 && jc >= 1 && jc < N1 - 1)) {
        int r = 2 * cy + 1, c = 2 * cx + 1;
        v = 4.f * (D0F * sP[r * 35 + c] - sP[(r - 1) * 35 + c] - sP[(r + 1) * 35 + c]
                   - sP[r * 35 + c - 1] - sP[r * 35 + c + 1] + sQ[(r + 1) * 37 + c + 1]);
      }
      q1p[cbase + (size_t)ic * N1 + jc] = v;
    }
  }
}

__global__ __launch_bounds__(NT) void drelaxR_k(
    const float* __restrict__ psi, const float* __restrict__ Qg,
    float* __restrict__ out, float* __restrict__ q1) {
  __shared__ float smem[38 * 39 + 36 * 37 + 36 * 37];
  float* sIn = smem;
  float* sQ  = smem + 38 * 39;
  float* sT  = sQ + 36 * 37;
  float* sP  = smem;               // alias sIn (dead after s1)
  int bx = blockIdx.x, by = blockIdx.y;
  int ti = by * 32, tj = bx * 32;
  size_t base = (size_t)blockIdx.z * (N0 * N0);
  size_t cbase = (size_t)blockIdx.z * (N1 * N1);
  int lid = threadIdx.y * 32 + threadIdx.x;
  bool inter = (bx >= 1 && bx <= 14 && by >= 1 && by <= 14);
  if (inter)
    drelaxR_body<true>(psi + base, Qg + base, out, q1, ti, tj, 16 * by, 16 * bx,
                       base, cbase, lid, sIn, sQ, sT, sP);
  else
    drelaxR_body<false>(psi + base, Qg + base, out, q1, ti, tj, 16 * by, 16 * bx,
                        base, cbase, lid, sIn, sQ, sT, sP);
}

// ------------------------------------------------------- shared coarse prep --
template<bool INT>
__device__ __forceinline__ void coarse_and_v(
    const float* __restrict__ P, const float* __restrict__ Q,
    const float* __restrict__ q1,
    int ti, int tj, int c0i, int c0j, int lid,
    float* __restrict__ bufA, float* __restrict__ bufB,
    float* __restrict__ sq1, float* __restrict__ sp1) {
  const int n = N0;
  if constexpr (INT) {
    stage_v<25, 25, 26, N1, false>(q1, c0i - 1, c0j - 1, sq1, lid);
    stage_v<40, 40, 41, N0, true>(Q, ti - 4, tj - 4, bufB, lid);
    __syncthreads();
    for (int t = lid; t < 23 * 23; t += NT) {
      int r = t / 23, c = t - r * 23;
      sp1[r * 24 + c] = C1F * (-C1F * (sq1[r * 26 + c + 1] + sq1[(r + 2) * 26 + c + 1] +
                                       sq1[(r + 1) * 26 + c] + sq1[(r + 1) * 26 + c + 2])
                               - sq1[(r + 1) * 26 + c + 1]);
    }
    __syncthreads();
    prolong_v(P, sp1, bufA, ti, tj, c0i, c0j, lid);
    __syncthreads();
  } else {
    for (int t = lid; t < 25 * 25; t += NT) {
      int r = t / 25, c = t - r * 25;
      int ci = c0i - 1 + r, cj = c0j - 1 + c;
      sq1[r * 26 + c] = (ci >= 0 && ci < N1 && cj >= 0 && cj < N1) ? q1[(size_t)ci * N1 + cj] : 0.f;
    }
    for (int t = lid; t < 40 * 40; t += NT) {
      int r = t / 40, c = t - r * 40;
      int gi = ti - 4 + r, gj = tj - 4 + c;
      bufB[r * 41 + c] = (gi >= 0 && gi < n && gj >= 0 && gj < n) ? Q[(size_t)gi * n + gj] * H0SQ : 0.f;
    }
    __syncthreads();
    for (int t = lid; t < 23 * 23; t += NT) {
      int r = t / 23, c = t - r * 23;
      float v = 0.f;
      if ((c0i + r) >= 1 && (c0i + r) < N1 - 1 && (c0j + c) >= 1 && (c0j + c) < N1 - 1)
        v = C1F * (-C1F * (sq1[r * 26 + c + 1] + sq1[(r + 2) * 26 + c + 1] +
                           sq1[(r + 1) * 26 + c] + sq1[(r + 1) * 26 + c + 2])
                   - sq1[(r + 1) * 26 + c + 1]);
      sp1[r * 24 + c] = v;
    }
    __syncthreads();
    for (int t = lid; t < 42 * 42; t += NT) {
      int r = t / 42, c = t - r * 42;
      int gi = ti - 5 + r, gj = tj - 5 + c;
      float v = 0.f;
      if (gi >= 0 && gi < n && gj >= 0 && gj < n) {
        int r1 = (gi >> 1) - c0i, c1 = (gj >> 1) - c0j;
        float a = sp1[r1 * 24 + c1],       b = sp1[r1 * 24 + c1 + 1];
        float e = sp1[(r1 + 1) * 24 + c1], d = sp1[(r1 + 1) * 24 + c1 + 1];
        float wx = (gj & 1) ? 0.5f : 0.f, wy = (gi & 1) ? 0.5f : 0.f;
        float r0 = a + wx * (b - a), rr = e + wx * (d - e);
        v = P[(size_t)gi * n + gj] + (r0 + wy * (rr - r0));
      }
      bufA[r * 43 + c] = v;
    }
    __syncthreads();
  }
}

// ------------------------------------------------------------------- vleg ---
template<bool INT>
__device__ __forceinline__ void vleg_body(
    const float* __restrict__ P, const float* __restrict__ Q,
    const float* __restrict__ q1, float* __restrict__ outp, float* __restrict__ q1o,
    int ti, int tj, int c0i, int c0j, int ic0, int jc0,
    size_t base, size_t cbase, int lid,
    float* __restrict__ bufA, float* __restrict__ bufB,
    float* __restrict__ bufC, float* __restrict__ bufD) {
  const int n = N0;
  coarse_and_v<INT>(P, Q, q1, ti, tj, c0i, c0j, lid, bufA, bufB, bufD, bufD + 25 * 26);
  if constexpr (INT) {
    sweep_v<40, 40, 43, 41, 41, false>(bufA, bufB, bufC, lid);         // s1
    __syncthreads();
    sweep_v<38, 38, 41, 41, 39, false>(bufC, bufB + 42, bufD, lid);    // s2
    __syncthreads();
    sweep_v<36, 36, 39, 41, 37, false>(bufD, bufB + 84, bufA, lid);    // s3
    __syncthreads();
    sweep_v_store<37, 41, 35>(bufA, bufB + 126, bufC, outp + base, ti, tj, lid);
    __syncthreads();
  } else {
    for (int t = lid; t < 40 * 40; t += NT) {   // s1
      int r = t / 40, c = t - r * 40;
      float v = 0.f;
      if ((ti - 4 + r) >= 1 && (ti - 4 + r) < n - 1 && (tj - 4 + c) >= 1 && (tj - 4 + c) < n - 1)
        v = C0F * (bufA[r * 43 + c + 1] + bufA[(r + 2) * 43 + c + 1] +
                   bufA[(r + 1) * 43 + c] + bufA[(r + 1) * 43 + c + 2] - bufB[r * 41 + c]);
      bufC[r * 41 + c] = v;
    }
    __syncthreads();
    for (int t = lid; t < 38 * 38; t += NT) {   // s2
      int r = t / 38, c = t - r * 38;
      float v = 0.f;
      if ((ti - 3 + r) >= 1 && (ti - 3 + r) < n - 1 && (tj - 3 + c) >= 1 && (tj - 3 + c) < n - 1)
        v = C0F * (bufC[r * 41 + c + 1] + bufC[(r + 2) * 41 + c + 1] +
                   bufC[(r + 1) * 41 + c] + bufC[(r + 1) * 41 + c + 2] - bufB[(r + 1) * 41 + c + 1]);
      bufD[r * 39 + c] = v;
    }
    __syncthreads();
    for (int t = lid; t < 36 * 36; t += NT) {   // s3
      int r = t / 36, c = t - r * 36;
      float v = 0.f;
      if ((ti - 2 + r) >= 1 && (ti - 2 + r) < n - 1 && (tj - 2 + c) >= 1 && (tj - 2 + c) < n - 1)
        v = C0F * (bufD[r * 39 + c + 1] + bufD[(r + 2) * 39 + c + 1] +
                   bufD[(r + 1) * 39 + c] + bufD[(r + 1) * 39 + c + 2] - bufB[(r + 2) * 41 + c + 2]);
      bufA[r * 37 + c] = v;
    }
    __syncthreads();
    for (int t = lid; t < 34 * 34; t += NT) {   // s4 + store
      int r = t / 34, c = t - r * 34;
      float v = 0.f;
      if ((ti - 1 + r) >= 1 && (ti - 1 + r) < n - 1 && (tj - 1 + c) >= 1 && (tj - 1 + c) < n - 1)
        v = C0F * (bufA[r * 37 + c + 1] + bufA[(r + 2) * 37 + c + 1] +
                   bufA[(r + 1) * 37 + c] + bufA[(r + 1) * 37 + c + 2] - bufB[(r + 3) * 41 + c + 3]);
      bufC[r * 35 + c] = v;
      if (r >= 1 && r <= 32 && c >= 1 && c <= 32 && (ti - 1 + r) < n && (tj - 1 + c) < n)
        outp[base + (size_t)(ti - 1 + r) * n + (tj - 1 + c)] = v;
    }
    __syncthreads();
  }
  if (lid < 256) {
    int cy = lid >> 4, cx = lid & 15;
    int ic = ic0 + cy, jc = jc0 + cx;
    if (INT || (ic < N1 && jc < N1)) {
      float v = 0.f;
      if (INT || (ic >= 1 && ic < N1 - 1 && jc >= 1 && jc < N1 - 1)) {
        int r = 2 * cy + 1, c = 2 * cx + 1;
        v = 4.f * (D0F * bufC[r * 35 + c] - bufC[(r - 1) * 35 + c] - bufC[(r + 1) * 35 + c]
                   - bufC[r * 35 + c - 1] - bufC[r * 35 + c + 1]
                   + bufB[(2 * cy + 4) * 41 + 2 * cx + 4]);
      }
      q1o[cbase + (size_t)ic * N1 + jc] = v;
    }
  }
}

__global__ __launch_bounds__(NT) void vleg_k(
    const float* __restrict__ psi, const float* __restrict__ Qg,
    const float* __restrict__ q1g, float* __restrict__ out, float* __restrict__ q1o) {
  __shared__ float bufA[42 * 43];
  __shared__ float bufB[40 * 41];
  __shared__ float bufC[40 * 41];
  __shared__ float bufD[38 * 39];
  int bx = blockIdx.x, by = blockIdx.y;
  int ti = by * 32, tj = bx * 32;
  int c0i = 16 * by - 3, c0j = 16 * bx - 3;
  size_t base = (size_t)blockIdx.z * (N0 * N0);
  size_t cbase = (size_t)blockIdx.z * (N1 * N1);
  const float* q1 = q1g + cbase;
  int lid = threadIdx.y * 32 + threadIdx.x;
  bool inter = (bx >= 1 && bx <= 14 && by >= 1 && by <= 14);
  if (inter)
    vleg_body<true>(psi + base, Qg + base, q1, out, q1o, ti, tj, c0i, c0j,
                    16 * by, 16 * bx, base, cbase, lid, bufA, bufB, bufC, bufD);
  else
    vleg_body<false>(psi + base, Qg + base, q1, out, q1o, ti, tj, c0i, c0j,
                     16 * by, 16 * bx, base, cbase, lid, bufA, bufB, bufC, bufD);
}

// ------------------------------------------------------------------- mega ---
template<bool INT>
__device__ __forceinline__ void mega_body(
    const float* __restrict__ P, const float* __restrict__ Q,
    const float* __restrict__ q1, const float* __restrict__ CT,
    float* __restrict__ psi_out, float* __restrict__ qf_out,
    int ti, int tj, int c0i, int c0j, size_t base, int lid,
    float* __restrict__ bufA, float* __restrict__ bufB,
    float* __restrict__ bufC, float* __restrict__ bufD) {
  const int n = N0;
  coarse_and_v<INT>(P, Q, q1, ti, tj, c0i, c0j, lid, bufA, bufB, bufD, bufD + 25 * 26);
  if constexpr (INT) {
    sweep_v<40, 40, 43, 41, 41, false>(bufA, bufB, bufC, lid);         // s1
    __syncthreads();
    sweep_v<38, 38, 41, 41, 39, false>(bufC, bufB + 42, bufD, lid);    // s2
    __syncthreads();
    sweep_v<36, 36, 39, 41, 37, true>(bufD, bufB, bufA, lid);          // Z
    __syncthreads();
    sweep_v<34, 34, 37, 41, 35, true>(bufA, bufB, bufC, lid);          // Z2
    __syncthreads();
  } else {
    for (int t = lid; t < 40 * 40; t += NT) {   // s1
      int r = t / 40, c = t - r * 40;
      float v = 0.f;
      if ((ti - 4 + r) >= 1 && (ti - 4 + r) < n - 1 && (tj - 4 + c) >= 1 && (tj - 4 + c) < n - 1)
        v = C0F * (bufA[r * 43 + c + 1] + bufA[(r + 2) * 43 + c + 1] +
                   bufA[(r + 1) * 43 + c] + bufA[(r + 1) * 43 + c + 2] - bufB[r * 41 + c]);
      bufC[r * 41 + c] = v;
    }
    __syncthreads();
    for (int t = lid; t < 38 * 38; t += NT) {   // s2
      int r = t / 38, c = t - r * 38;
      float v = 0.f;
      if ((ti - 3 + r) >= 1 && (ti - 3 + r) < n - 1 && (tj - 3 + c) >= 1 && (tj - 3 + c) < n - 1)
        v = C0F * (bufC[r * 41 + c + 1] + bufC[(r + 2) * 41 + c + 1] +
                   bufC[(r + 1) * 41 + c] + bufC[(r + 1) * 41 + c + 2] - bufB[(r + 1) * 41 + c + 1]);
      bufD[r * 39 + c] = v;
    }
    __syncthreads();
    for (int t = lid; t < 36 * 36; t += NT) {   // Z
      int r = t / 36, c = t - r * 36;
      float v = 0.f;
      if ((ti - 2 + r) >= 1 && (ti - 2 + r) < n - 1 && (tj - 2 + c) >= 1 && (tj - 2 + c) < n - 1)
        v = (bufD[r * 39 + c + 1] + bufD[(r + 2) * 39 + c + 1] +
             bufD[(r + 1) * 39 + c] + bufD[(r + 1) * 39 + c + 2]) * INV_DX2
            - bufD[(r + 1) * 39 + c + 1] * CENTER;
      bufA[r * 37 + c] = v;
    }
    __syncthreads();
    for (int t = lid; t < 34 * 34; t += NT) {   // Z2
      int r = t / 34, c = t - r * 34;
      float v = 0.f;
      if ((ti - 1 + r) >= 1 && (ti - 1 + r) < n - 1 && (tj - 1 + c) >= 1 && (tj - 1 + c) < n - 1)
        v = (bufA[r * 37 + c + 1] + bufA[(r + 2) * 37 + c + 1] +
             bufA[(r + 1) * 37 + c] + bufA[(r + 1) * 37 + c + 2]) * INV_DX2
            - bufA[(r + 1) * 37 + c + 1] * CENTER;
      bufC[r * 35 + c] = v;
    }
    __syncthreads();
  }
  int tx = lid & 31, ty = lid >> 5;
  #pragma unroll
  for (int s = 0; s < 2; s++) {
    int yy = ty + 16 * s;
    int i = ti + yy, j = tj + tx;
    if (!INT && (i >= n || j >= n)) continue;
    size_t idx = base + (size_t)i * n + j;
    int pr = yy + 3, pc = tx + 3;
    psi_out[idx] = bufD[pr * 39 + pc];
    float qv = 0.f;
    if (INT || (i >= 1 && i < n - 1 && j >= 1 && j < n - 1)) {
      float z1v = bufA[(yy + 2) * 37 + tx + 2];
      int r2 = yy + 1, c2 = tx + 1;
      float z2v = bufC[r2 * 35 + c2];
      float z4 = (bufC[r2 * 35 + c2 - 1] + bufC[r2 * 35 + c2 + 1] +
                  bufC[(r2 - 1) * 35 + c2] + bufC[(r2 + 1) * 35 + c2]) * INV_DX2
                 - z2v * CENTER;
      float Amm = bufD[(pr - 1) * 39 + pc - 1], Am0 = bufD[(pr - 1) * 39 + pc],
            Amp = bufD[(pr - 1) * 39 + pc + 1];
      float A0m = bufD[pr * 39 + pc - 1], A0p = bufD[pr * 39 + pc + 1];
      float Apm = bufD[(pr + 1) * 39 + pc - 1], Ap0 = bufD[(pr + 1) * 39 + pc],
            App = bufD[(pr + 1) * 39 + pc + 1];
      int qr = yy + 4, qc = tx + 4;
      float J = (A0m - Am0) * bufB[(qr - 1) * 41 + qc - 1]
              + (Amm + A0m - Amp - A0p) * bufB[(qr - 1) * 41 + qc]
              + (Am0 - A0p) * bufB[(qr - 1) * 41 + qc + 1]
              + (Apm + Ap0 - Amm - Am0) * bufB[qr * 41 + qc - 1]
              + (Am0 + Amp - Ap0 - App) * bufB[qr * 41 + qc + 1]
              + (Ap0 - A0m) * bufB[(qr + 1) * 41 + qc - 1]
              + (A0p + App - A0m - Apm) * bufB[(qr + 1) * 41 + qc]
              + (A0p - Ap0) * bufB[(qr + 1) * 41 + qc + 1];
      J *= INV12S;
      float ct = CT[(size_t)i * n + j];
      qv = -J - 1e-6f * z1v + 1e-8f * z2v - 2e-11f * z4 + ct - 256.0f * (A0p - A0m);
    }
    qf_out[idx] = qv;
  }
}

__global__ __launch_bounds__(NT) void mega_k(
    const float* __restrict__ psi, const float* __restrict__ Qg,
    const float* __restrict__ q1g, const float* __restrict__ CT,
    float* __restrict__ psi_out, float* __restrict__ qf_out) {
  __shared__ float bufA[42 * 43];
  __shared__ float bufB[40 * 41];
  __shared__ float bufC[40 * 41];
  __shared__ float bufD[38 * 39];
  int bx = blockIdx.x, by = blockIdx.y;
  int ti = by * 32, tj = bx * 32;
  int c0i = 16 * by - 3, c0j = 16 * bx - 3;
  size_t base = (size_t)blockIdx.z * (N0 * N0);
  const float* q1 = q1g + (size_t)blockIdx.z * (N1 * N1);
  int lid = threadIdx.y * 32 + threadIdx.x;
  bool inter = (bx >= 1 && bx <= 14 && by >= 1 && by <= 14);
  if (inter)
    mega_body<true>(psi + base, Qg + base, q1, CT, psi_out, qf_out,
                    ti, tj, c0i, c0j, base, lid, bufA, bufB, bufC, bufD);
  else
    mega_body<false>(psi + base, Qg + base, q1, CT, psi_out, qf_out,
                     ti, tj, c0i, c0j, base, lid, bufA, bufB, bufC, bufD);
}

extern "C" void kernel_launch(void* const* d_in, const int* in_sizes, int n_in,
                              void* d_out, int out_size, void* d_ws, size_t ws_size,
                              hipStream_t stream) {
  const float* PSIG = (const float*)d_in[1];
  const float* Q    = (const float*)d_in[2];
  const float* CT   = (const float*)d_in[3];

  float* ws = (float*)d_ws;
  size_t f0 = (size_t)NB * N0 * N0;
  size_t f1 = (size_t)NB * N1 * N1;
  float* pA  = ws;
  float* pB  = pA + f0;
  float* q1a = pB + f0;
  float* q1b = q1a + f1;

  dim3 blk(32, 16, 1), grd(17, 17, NB);

  drelaxR_k<<<grd, blk, 0, stream>>>(PSIG, Q, pA, q1a);      // cycle-1 down
  vleg_k<<<grd, blk, 0, stream>>>(pA, Q, q1a, pB, q1b);      // c1 up + c2 down
  float* psi_out = (float*)d_out;
  float* qf_out  = psi_out + f0;
  mega_k<<<grd, blk, 0, stream>>>(pB, Q, q1b, CT, psi_out, qf_out);  // c2 up + flux
}